// Round 12
// baseline (77.254 us; speedup 1.0000x reference)
//
#include <hip/hip_runtime.h>

#define N_USER   100000
#define N_ITEM   200000
#define N_NODES  300000
#define NNZ      4000000
#define EMB      64
#define N_LAYERS 3
#define BATCH    4096
#define NSLOT    (3*BATCH)   // 12288
#define MAXE     96          // bucket capacity; edges/node ~ Poisson(13.3)
#define HCAP     256         // hits per 2048-edge block ~ N(84,9) -> 19 sigma
#define BMWORDS  9376        // ceil(300000/32)

// ---------------- ws layout ----------------
// [0]         u16  table16[N_NODES]       600,000 B (pad 600,064)  -- NEVER cleared (bitmap-gated)
// [600064]    int  count[NSLOT]           49,152 B
// [649216]    int2 csr2[NSLOT*MAXE]       9,437,184 B  (col, val-bits)
// [10086400]  uint bitmap[BMWORDS]        37,504 B (pad 37,632)

#define BM4    2344      // 37,504/16

// clear only the bitmap (37.5 KB); count is cleared by k_setup (1:1 threads)
__global__ void __launch_bounds__(256) k_clear(int4* __restrict__ b4) {
    int i = blockIdx.x * blockDim.x + threadIdx.x;
    if (i < BM4) b4[i] = make_int4(0, 0, 0, 0);
}

__global__ void k_setup(const int* __restrict__ users,
                        const int* __restrict__ pos,
                        const int* __restrict__ neg,
                        unsigned short* __restrict__ table16,
                        unsigned int* __restrict__ bitmap,
                        int* __restrict__ count) {
    int i = blockIdx.x * blockDim.x + threadIdx.x;
    if (i >= NSLOT) return;
    count[i] = 0;
    int node;
    if (i < BATCH)            node = users[i];
    else if (i < 2 * BATCH)   node = N_USER + pos[i - BATCH];
    else                      node = N_USER + neg[i - 2 * BATCH];
    table16[node] = (unsigned short)i;        // benign race on duplicates (winner consistent)
    atomicOr(&bitmap[((unsigned)node) >> 5], 1u << (node & 31));
}

// stream row+col+vals coalesced (8 edges/thread); membership via 37.5 KB bitmap
// (L1-resident) so only ~4.3% of lanes pay the table16 L2 gather; LDS-compact
// hits; phase B wave-dense: one count atomic + one int2 store per hit.
__global__ void __launch_bounds__(256) k_build(
        const int* __restrict__ row,
        const int* __restrict__ col,
        const float* __restrict__ vals,
        const unsigned int* __restrict__ bitmap,
        const unsigned short* __restrict__ table16,
        int* __restrict__ count,
        int2* __restrict__ csr2) {
    __shared__ int   ls_s[HCAP];
    __shared__ int   ls_c[HCAP];
    __shared__ float ls_v[HCAP];
    __shared__ int   cnt;
    int tid = threadIdx.x;
    if (tid == 0) cnt = 0;
    __syncthreads();

    const int nt4 = NNZ / 4;                  // 1,000,000 int4 tiles
    #pragma unroll
    for (int q = 0; q < 2; ++q) {
        int t = blockIdx.x * 512 + q * 256 + tid;
        if (t < nt4) {
            int4   r = ((const int4*)row)[t];
            int4   c = ((const int4*)col)[t];
            float4 v = ((const float4*)vals)[t];
            bool h0 = (bitmap[((unsigned)r.x) >> 5] >> (r.x & 31)) & 1;
            bool h1 = (bitmap[((unsigned)r.y) >> 5] >> (r.y & 31)) & 1;
            bool h2 = (bitmap[((unsigned)r.z) >> 5] >> (r.z & 31)) & 1;
            bool h3 = (bitmap[((unsigned)r.w) >> 5] >> (r.w & 31)) & 1;
            int rr[4] = { r.x, r.y, r.z, r.w };
            int cc[4] = { c.x, c.y, c.z, c.w };
            float vv[4] = { v.x, v.y, v.z, v.w };
            bool hh[4] = { h0, h1, h2, h3 };
            #pragma unroll
            for (int i = 0; i < 4; ++i) {
                if (hh[i]) {
                    int si = (int)table16[rr[i]];   // only hits touch the table
                    int p = atomicAdd(&cnt, 1);     // LDS atomic
                    if (p < HCAP) { ls_s[p] = si; ls_c[p] = cc[i]; ls_v[p] = vv[i]; }
                    else {                          // statistically never (19 sigma)
                        int pp = atomicAdd(&count[si], 1);
                        if (pp < MAXE)
                            csr2[(size_t)si * MAXE + pp] = make_int2(cc[i], __float_as_int(vv[i]));
                    }
                }
            }
        }
    }
    __syncthreads();

    int n = cnt; n = (n < HCAP) ? n : HCAP;
    for (int t2 = tid; t2 < n; t2 += 256) {
        int si = ls_s[t2];
        int p = atomicAdd(&count[si], 1);
        if (p < MAXE)
            csr2[(size_t)si * MAXE + p] = make_int2(ls_c[t2], __float_as_int(ls_v[t2]));
    }
}

// fused gather + MLP: 4 slots/wave, 16/block. Per slot: lane-parallel csr2 load
// + shfl-broadcast coalesced embedding gather into registers; then 3 layers with
// block-staged W and readlane broadcasts. No side buffer.
__global__ void __launch_bounds__(256) k_gmlp(
        const int* __restrict__ users,
        const int* __restrict__ pos,
        const int* __restrict__ neg,
        const float* __restrict__ user_emb,
        const float* __restrict__ item_emb,
        const float* __restrict__ W_gc,
        const float* __restrict__ b_gc,
        const float* __restrict__ W_bi,
        const float* __restrict__ b_bi,
        const unsigned short* __restrict__ table16,
        const int* __restrict__ count,
        const int2* __restrict__ csr2,
        float* __restrict__ out) {
    __shared__ float wg[EMB * EMB];
    __shared__ float wb[EMB * EMB];
    int tid = threadIdx.x;
    int w = tid >> 6;
    int j = tid & 63;
    int sbase = blockIdx.x * 16 + w * 4;

    // stage layer-0 weights early; __syncthreads comes after the gather
    {
        const float4* g4 = (const float4*)W_gc;
        const float4* b4 = (const float4*)W_bi;
        float4* lg = (float4*)wg;
        float4* lb = (float4*)wb;
        #pragma unroll
        for (int i2 = tid; i2 < EMB * EMB / 4; i2 += 256) { lg[i2] = g4[i2]; lb[i2] = b4[i2]; }
    }

    float sval[4], e[4];
    #pragma unroll
    for (int s = 0; s < 4; ++s) {
        int slot = sbase + s;
        int node;
        if (slot < BATCH)          node = users[slot];
        else if (slot < 2 * BATCH) node = N_USER + pos[slot - BATCH];
        else                       node = N_USER + neg[slot - 2 * BATCH];
        const float* erow = (node < N_USER) ? (user_emb + (size_t)node * EMB)
                                            : (item_emb + (size_t)(node - N_USER) * EMB);
        e[s] = erow[j];
        out[(size_t)slot * 256 + j] = e[s];       // layer-0 columns: raw ego

        int wslot = (int)table16[node];           // winner slot (always marked)
        wslot = __builtin_amdgcn_readfirstlane(wslot);
        int n = count[wslot];
        n = (n < MAXE) ? n : MAXE;
        n = __builtin_amdgcn_readfirstlane(n);
        const int2* base = csr2 + (size_t)wslot * MAXE;

        float acc = 0.f;
        for (int t0 = 0; t0 < n; t0 += 64) {
            int idx = t0 + j;
            int2 ev = make_int2(0, 0);
            if (idx < n) ev = base[idx];          // lane j holds edge t0+j
            int m = n - t0; m = (m < 64) ? m : 64;
            for (int tt = 0; tt < m; tt += 16) {
                float vv[16], gg[16];
                #pragma unroll
                for (int k = 0; k < 16; ++k) {
                    int  t  = tt + k;
                    bool okk = t < m;
                    int   cc = __shfl(ev.x, t, 64);
                    float vb = __uint_as_float((unsigned)__shfl(ev.y, t, 64));
                    vv[k] = okk ? vb : 0.f;
                    int ci = okk ? cc : 0;
                    const float* sp = (ci < N_USER) ? (user_emb + (size_t)ci * EMB)
                                                    : (item_emb + (size_t)(ci - N_USER) * EMB);
                    gg[k] = sp[j];                // coalesced 256 B per k
                }
                #pragma unroll
                for (int k = 0; k < 16; ++k) acc = fmaf(vv[k], gg[k], acc);
            }
        }
        sval[s] = acc;
    }

    for (int k = 0; k < N_LAYERS; ++k) {
        if (k == 0) {
            __syncthreads();                      // layer-0 weights staged
        } else {
            __syncthreads();                      // prev-layer LDS reads done
            const float4* g4 = (const float4*)(W_gc + (size_t)k * EMB * EMB);
            const float4* b4 = (const float4*)(W_bi + (size_t)k * EMB * EMB);
            float4* lg = (float4*)wg;
            float4* lb = (float4*)wb;
            #pragma unroll
            for (int i2 = tid; i2 < EMB * EMB / 4; i2 += 256) { lg[i2] = g4[i2]; lb[i2] = b4[i2]; }
            __syncthreads();                      // weights ready
        }

        float b1 = b_gc[k * EMB + j];
        float b2 = b_bi[k * EMB + j];
        float sum1[4], sum2[4], pv[4];
        #pragma unroll
        for (int s = 0; s < 4; ++s) { sum1[s] = b1; sum2[s] = b2; pv[s] = sval[s] * e[s]; }

        #pragma unroll 8
        for (int i = 0; i < EMB; ++i) {
            float wgi = wg[i * EMB + j];
            float wbi = wb[i * EMB + j];
            #pragma unroll
            for (int s = 0; s < 4; ++s) {
                float si = __uint_as_float(__builtin_amdgcn_readlane(__float_as_uint(sval[s]), i));
                float pi = __uint_as_float(__builtin_amdgcn_readlane(__float_as_uint(pv[s]),   i));
                sum1[s] = fmaf(si, wgi, sum1[s]);
                sum2[s] = fmaf(pi, wbi, sum2[s]);
            }
        }

        #pragma unroll
        for (int s = 0; s < 4; ++s) {
            float x = sum1[s] + sum2[s];
            x = (x >= 0.f) ? x : 0.2f * x;        // leaky_relu 0.2
            float sq = x * x;                     // wave-wide L2 norm
            #pragma unroll
            for (int o = 32; o; o >>= 1) sq += __shfl_xor(sq, o, 64);
            float nn = fmaxf(sqrtf(sq), 1e-12f);
            out[(size_t)(sbase + s) * 256 + (k + 1) * 64 + j] = x / nn;
            e[s] = x;                             // next-layer ego = unnormalized output
        }
    }
}

extern "C" void kernel_launch(void* const* d_in, const int* in_sizes, int n_in,
                              void* d_out, int out_size, void* d_ws, size_t ws_size,
                              hipStream_t stream) {
    const int*   users    = (const int*)  d_in[0];
    const int*   pos      = (const int*)  d_in[1];
    const int*   neg      = (const int*)  d_in[2];
    const int*   row      = (const int*)  d_in[3];
    const int*   col      = (const int*)  d_in[4];
    const float* vals     = (const float*)d_in[5];
    const float* user_emb = (const float*)d_in[6];
    const float* item_emb = (const float*)d_in[7];
    const float* W_gc     = (const float*)d_in[8];
    const float* b_gc     = (const float*)d_in[9];
    const float* W_bi     = (const float*)d_in[10];
    const float* b_bi     = (const float*)d_in[11];
    float* out = (float*)d_out;

    char* ws = (char*)d_ws;
    unsigned short* table16 = (unsigned short*)ws;
    int*            count   = (int*)(ws + 600064);
    int2*           csr2    = (int2*)(ws + 649216);
    unsigned int*   bitmap  = (unsigned int*)(ws + 10086400);

    k_clear<<<(BM4 + 255) / 256, 256, 0, stream>>>((int4*)bitmap);
    k_setup<<<(NSLOT + 255) / 256, 256, 0, stream>>>(users, pos, neg, table16,
                                                     bitmap, count);
    k_build<<<(NNZ / 4 + 511) / 512, 256, 0, stream>>>(row, col, vals, bitmap,
                                                       table16, count, csr2);
    k_gmlp<<<NSLOT / 16, 256, 0, stream>>>(users, pos, neg, user_emb, item_emb,
                                           W_gc, b_gc, W_bi, b_bi,
                                           table16, count, csr2, out);
}

// Round 13
// 76.248 us; speedup vs baseline: 1.0132x; 1.0132x over previous
//
#include <hip/hip_runtime.h>

#define N_USER   100000
#define N_ITEM   200000
#define N_NODES  300000
#define NNZ      4000000
#define EMB      64
#define N_LAYERS 3
#define BATCH    4096
#define NSLOT    (3*BATCH)   // 12288
#define MAXE     96          // bucket capacity; edges/node ~ Poisson(13.3)
#define HCAP     256         // hits per 2048-edge block ~ N(84,9) -> 19 sigma
#define BMWORDS  9376        // ceil(300000/32)

// ---------------- ws layout ----------------
// [0]         u16  table16[N_NODES]       600,000 B (pad 600,064)  -- NEVER cleared (bitmap-gated)
// [600064]    int  count[NSLOT]           49,152 B
// [649216]    int2 csr2[NSLOT*MAXE]       9,437,184 B  (col, val-bits)
// [10086400]  uint bitmap[BMWORDS]        37,504 B (pad 37,632)

#define BM4    2344      // 37,504/16

__global__ void __launch_bounds__(256) k_clear(int4* __restrict__ b4) {
    int i = blockIdx.x * blockDim.x + threadIdx.x;
    if (i < BM4) b4[i] = make_int4(0, 0, 0, 0);
}

__global__ void k_setup(const int* __restrict__ users,
                        const int* __restrict__ pos,
                        const int* __restrict__ neg,
                        unsigned short* __restrict__ table16,
                        unsigned int* __restrict__ bitmap,
                        int* __restrict__ count) {
    int i = blockIdx.x * blockDim.x + threadIdx.x;
    if (i >= NSLOT) return;
    count[i] = 0;
    int node;
    if (i < BATCH)            node = users[i];
    else if (i < 2 * BATCH)   node = N_USER + pos[i - BATCH];
    else                      node = N_USER + neg[i - 2 * BATCH];
    table16[node] = (unsigned short)i;        // benign race on duplicates (winner consistent)
    atomicOr(&bitmap[((unsigned)node) >> 5], 1u << (node & 31));
}

// stream row+col+vals coalesced (8 edges/thread); bitmap gate (L1-resident);
// LDS-compact hits; phase B wave-dense.
__global__ void __launch_bounds__(256) k_build(
        const int* __restrict__ row,
        const int* __restrict__ col,
        const float* __restrict__ vals,
        const unsigned int* __restrict__ bitmap,
        const unsigned short* __restrict__ table16,
        int* __restrict__ count,
        int2* __restrict__ csr2) {
    __shared__ int   ls_s[HCAP];
    __shared__ int   ls_c[HCAP];
    __shared__ float ls_v[HCAP];
    __shared__ int   cnt;
    int tid = threadIdx.x;
    if (tid == 0) cnt = 0;
    __syncthreads();

    const int nt4 = NNZ / 4;                  // 1,000,000 int4 tiles
    #pragma unroll
    for (int q = 0; q < 2; ++q) {
        int t = blockIdx.x * 512 + q * 256 + tid;
        if (t < nt4) {
            int4   r = ((const int4*)row)[t];
            int4   c = ((const int4*)col)[t];
            float4 v = ((const float4*)vals)[t];
            bool h0 = (bitmap[((unsigned)r.x) >> 5] >> (r.x & 31)) & 1;
            bool h1 = (bitmap[((unsigned)r.y) >> 5] >> (r.y & 31)) & 1;
            bool h2 = (bitmap[((unsigned)r.z) >> 5] >> (r.z & 31)) & 1;
            bool h3 = (bitmap[((unsigned)r.w) >> 5] >> (r.w & 31)) & 1;
            int rr[4] = { r.x, r.y, r.z, r.w };
            int cc[4] = { c.x, c.y, c.z, c.w };
            float vv[4] = { v.x, v.y, v.z, v.w };
            bool hh[4] = { h0, h1, h2, h3 };
            #pragma unroll
            for (int i = 0; i < 4; ++i) {
                if (hh[i]) {
                    int si = (int)table16[rr[i]];
                    int p = atomicAdd(&cnt, 1);
                    if (p < HCAP) { ls_s[p] = si; ls_c[p] = cc[i]; ls_v[p] = vv[i]; }
                    else {
                        int pp = atomicAdd(&count[si], 1);
                        if (pp < MAXE)
                            csr2[(size_t)si * MAXE + pp] = make_int2(cc[i], __float_as_int(vv[i]));
                    }
                }
            }
        }
    }
    __syncthreads();

    int n = cnt; n = (n < HCAP) ? n : HCAP;
    for (int t2 = tid; t2 < n; t2 += 256) {
        int si = ls_s[t2];
        int p = atomicAdd(&count[si], 1);
        if (p < MAXE)
            csr2[(size_t)si * MAXE + p] = make_int2(ls_c[t2], __float_as_int(ls_v[t2]));
    }
}

// fused gather + MLP, occupancy-tuned: 2 slots/wave, 8 slots/block, 1536 blocks
// (5 blocks/CU LDS-resident). Both slots' metadata chains issued before the
// embedding rounds; per-layer W staged in 32 KB LDS.
__global__ void __launch_bounds__(256) k_gmlp(
        const int* __restrict__ users,
        const int* __restrict__ pos,
        const int* __restrict__ neg,
        const float* __restrict__ user_emb,
        const float* __restrict__ item_emb,
        const float* __restrict__ W_gc,
        const float* __restrict__ b_gc,
        const float* __restrict__ W_bi,
        const float* __restrict__ b_bi,
        const unsigned short* __restrict__ table16,
        const int* __restrict__ count,
        const int2* __restrict__ csr2,
        float* __restrict__ out) {
    __shared__ float wg[EMB * EMB];
    __shared__ float wb[EMB * EMB];
    int tid = threadIdx.x;
    int w = tid >> 6;
    int j = tid & 63;
    int sbase = blockIdx.x * 8 + w * 2;

    // stage layer-0 weights early; sync comes after the gather
    {
        const float4* g4 = (const float4*)W_gc;
        const float4* b4 = (const float4*)W_bi;
        float4* lg = (float4*)wg;
        float4* lb = (float4*)wb;
        #pragma unroll
        for (int i2 = tid; i2 < EMB * EMB / 4; i2 += 256) { lg[i2] = g4[i2]; lb[i2] = b4[i2]; }
    }

    // ---- phase 1: issue both slots' metadata chains ----
    float e[2];
    int   n[2];
    const int2* base[2];
    int2  ev[2];
    #pragma unroll
    for (int s = 0; s < 2; ++s) {
        int slot = sbase + s;
        int node;
        if (slot < BATCH)          node = users[slot];
        else if (slot < 2 * BATCH) node = N_USER + pos[slot - BATCH];
        else                       node = N_USER + neg[slot - 2 * BATCH];
        const float* erow = (node < N_USER) ? (user_emb + (size_t)node * EMB)
                                            : (item_emb + (size_t)(node - N_USER) * EMB);
        e[s] = erow[j];
        out[(size_t)slot * 256 + j] = e[s];       // layer-0 columns: raw ego

        int wslot = (int)table16[node];
        wslot = __builtin_amdgcn_readfirstlane(wslot);
        int nn = count[wslot];
        nn = (nn < MAXE) ? nn : MAXE;
        n[s] = __builtin_amdgcn_readfirstlane(nn);
        base[s] = csr2 + (size_t)wslot * MAXE;
        ev[s] = make_int2(0, 0);
        if (j < n[s]) ev[s] = base[s][j];         // lane j holds edge j
    }

    // ---- phase 2: embedding-gather rounds for both slots ----
    float sval[2];
    #pragma unroll
    for (int s = 0; s < 2; ++s) {
        float acc = 0.f;
        int nn = n[s];
        // main: edges 0..min(nn,64) from the preloaded ev; 16-wide rounds
        int m = (nn < 64) ? nn : 64;
        for (int tt = 0; tt < m; tt += 16) {
            float vv[16], gg[16];
            #pragma unroll
            for (int k = 0; k < 16; ++k) {
                int  t  = tt + k;
                bool okk = t < m;
                int   cc = __shfl(ev[s].x, t, 64);
                float vb = __uint_as_float((unsigned)__shfl(ev[s].y, t, 64));
                vv[k] = okk ? vb : 0.f;
                int ci = okk ? cc : 0;
                const float* sp = (ci < N_USER) ? (user_emb + (size_t)ci * EMB)
                                                : (item_emb + (size_t)(ci - N_USER) * EMB);
                gg[k] = sp[j];                    // coalesced 256 B per k
            }
            #pragma unroll
            for (int k = 0; k < 16; ++k) acc = fmaf(vv[k], gg[k], acc);
        }
        // tail: edges 64..nn (rare, Poisson(13.3))
        for (int t = 64; t < nn; ++t) {
            int2 ee = base[s][t];
            const float* sp = (ee.x < N_USER) ? (user_emb + (size_t)ee.x * EMB)
                                              : (item_emb + (size_t)(ee.x - N_USER) * EMB);
            acc = fmaf(__uint_as_float((unsigned)ee.y), sp[j], acc);
        }
        sval[s] = acc;
    }

    // ---- phase 3: 3-layer MLP ----
    for (int k = 0; k < N_LAYERS; ++k) {
        if (k == 0) {
            __syncthreads();                      // layer-0 weights staged
        } else {
            __syncthreads();                      // prev-layer LDS reads done
            const float4* g4 = (const float4*)(W_gc + (size_t)k * EMB * EMB);
            const float4* b4 = (const float4*)(W_bi + (size_t)k * EMB * EMB);
            float4* lg = (float4*)wg;
            float4* lb = (float4*)wb;
            #pragma unroll
            for (int i2 = tid; i2 < EMB * EMB / 4; i2 += 256) { lg[i2] = g4[i2]; lb[i2] = b4[i2]; }
            __syncthreads();                      // weights ready
        }

        float b1 = b_gc[k * EMB + j];
        float b2 = b_bi[k * EMB + j];
        float sum1[2], sum2[2], pv[2];
        #pragma unroll
        for (int s = 0; s < 2; ++s) { sum1[s] = b1; sum2[s] = b2; pv[s] = sval[s] * e[s]; }

        #pragma unroll 8
        for (int i = 0; i < EMB; ++i) {
            float wgi = wg[i * EMB + j];
            float wbi = wb[i * EMB + j];
            #pragma unroll
            for (int s = 0; s < 2; ++s) {
                float si = __uint_as_float(__builtin_amdgcn_readlane(__float_as_uint(sval[s]), i));
                float pi = __uint_as_float(__builtin_amdgcn_readlane(__float_as_uint(pv[s]),   i));
                sum1[s] = fmaf(si, wgi, sum1[s]);
                sum2[s] = fmaf(pi, wbi, sum2[s]);
            }
        }

        #pragma unroll
        for (int s = 0; s < 2; ++s) {
            float x = sum1[s] + sum2[s];
            x = (x >= 0.f) ? x : 0.2f * x;        // leaky_relu 0.2
            float sq = x * x;                     // wave-wide L2 norm
            #pragma unroll
            for (int o = 32; o; o >>= 1) sq += __shfl_xor(sq, o, 64);
            float nn2 = fmaxf(sqrtf(sq), 1e-12f);
            out[(size_t)(sbase + s) * 256 + (k + 1) * 64 + j] = x / nn2;
            e[s] = x;                             // next-layer ego = unnormalized output
        }
    }
}

extern "C" void kernel_launch(void* const* d_in, const int* in_sizes, int n_in,
                              void* d_out, int out_size, void* d_ws, size_t ws_size,
                              hipStream_t stream) {
    const int*   users    = (const int*)  d_in[0];
    const int*   pos      = (const int*)  d_in[1];
    const int*   neg      = (const int*)  d_in[2];
    const int*   row      = (const int*)  d_in[3];
    const int*   col      = (const int*)  d_in[4];
    const float* vals     = (const float*)d_in[5];
    const float* user_emb = (const float*)d_in[6];
    const float* item_emb = (const float*)d_in[7];
    const float* W_gc     = (const float*)d_in[8];
    const float* b_gc     = (const float*)d_in[9];
    const float* W_bi     = (const float*)d_in[10];
    const float* b_bi     = (const float*)d_in[11];
    float* out = (float*)d_out;

    char* ws = (char*)d_ws;
    unsigned short* table16 = (unsigned short*)ws;
    int*            count   = (int*)(ws + 600064);
    int2*           csr2    = (int2*)(ws + 649216);
    unsigned int*   bitmap  = (unsigned int*)(ws + 10086400);

    k_clear<<<(BM4 + 255) / 256, 256, 0, stream>>>((int4*)bitmap);
    k_setup<<<(NSLOT + 255) / 256, 256, 0, stream>>>(users, pos, neg, table16,
                                                     bitmap, count);
    k_build<<<(NNZ / 4 + 511) / 512, 256, 0, stream>>>(row, col, vals, bitmap,
                                                       table16, count, csr2);
    k_gmlp<<<NSLOT / 8, 256, 0, stream>>>(users, pos, neg, user_emb, item_emb,
                                          W_gc, b_gc, W_bi, b_bi,
                                          table16, count, csr2, out);
}

// Round 14
// 76.182 us; speedup vs baseline: 1.0141x; 1.0009x over previous
//
#include <hip/hip_runtime.h>

#define N_USER   100000
#define N_ITEM   200000
#define N_NODES  300000
#define NNZ      4000000
#define EMB      64
#define N_LAYERS 3
#define BATCH    4096
#define NSLOT    (3*BATCH)   // 12288
#define MAXE     96          // bucket capacity; edges/node ~ Poisson(13.3)
#define HCAP     256         // hits per 2048-edge block ~ N(84,9) -> 19 sigma
#define BMWORDS  9376        // ceil(300000/32)

// ---------------- ws layout ----------------
// [0]         u16  table16[N_NODES]       600,000 B (pad 600,064)  -- NEVER cleared (bitmap-gated)
// [600064]    int  count[NSLOT]           49,152 B
// [649216]    int2 csr2[NSLOT*MAXE]       9,437,184 B  (col, val-bits)
// [10086400]  uint bitmap[BMWORDS]        37,504 B (pad 37,632)

#define BM4    2344      // 37,504/16

__global__ void __launch_bounds__(256) k_clear(int4* __restrict__ b4) {
    int i = blockIdx.x * blockDim.x + threadIdx.x;
    if (i < BM4) b4[i] = make_int4(0, 0, 0, 0);
}

__global__ void k_setup(const int* __restrict__ users,
                        const int* __restrict__ pos,
                        const int* __restrict__ neg,
                        unsigned short* __restrict__ table16,
                        unsigned int* __restrict__ bitmap,
                        int* __restrict__ count) {
    int i = blockIdx.x * blockDim.x + threadIdx.x;
    if (i >= NSLOT) return;
    count[i] = 0;
    int node;
    if (i < BATCH)            node = users[i];
    else if (i < 2 * BATCH)   node = N_USER + pos[i - BATCH];
    else                      node = N_USER + neg[i - 2 * BATCH];
    table16[node] = (unsigned short)i;        // benign race on duplicates (winner consistent)
    atomicOr(&bitmap[((unsigned)node) >> 5], 1u << (node & 31));
}

// stream row+col+vals coalesced (8 edges/thread); bitmap gate (L1-resident);
// LDS-compact hits; phase B wave-dense.
__global__ void __launch_bounds__(256) k_build(
        const int* __restrict__ row,
        const int* __restrict__ col,
        const float* __restrict__ vals,
        const unsigned int* __restrict__ bitmap,
        const unsigned short* __restrict__ table16,
        int* __restrict__ count,
        int2* __restrict__ csr2) {
    __shared__ int   ls_s[HCAP];
    __shared__ int   ls_c[HCAP];
    __shared__ float ls_v[HCAP];
    __shared__ int   cnt;
    int tid = threadIdx.x;
    if (tid == 0) cnt = 0;
    __syncthreads();

    const int nt4 = NNZ / 4;                  // 1,000,000 int4 tiles
    #pragma unroll
    for (int q = 0; q < 2; ++q) {
        int t = blockIdx.x * 512 + q * 256 + tid;
        if (t < nt4) {
            int4   r = ((const int4*)row)[t];
            int4   c = ((const int4*)col)[t];
            float4 v = ((const float4*)vals)[t];
            bool h0 = (bitmap[((unsigned)r.x) >> 5] >> (r.x & 31)) & 1;
            bool h1 = (bitmap[((unsigned)r.y) >> 5] >> (r.y & 31)) & 1;
            bool h2 = (bitmap[((unsigned)r.z) >> 5] >> (r.z & 31)) & 1;
            bool h3 = (bitmap[((unsigned)r.w) >> 5] >> (r.w & 31)) & 1;
            int rr[4] = { r.x, r.y, r.z, r.w };
            int cc[4] = { c.x, c.y, c.z, c.w };
            float vv[4] = { v.x, v.y, v.z, v.w };
            bool hh[4] = { h0, h1, h2, h3 };
            #pragma unroll
            for (int i = 0; i < 4; ++i) {
                if (hh[i]) {
                    int si = (int)table16[rr[i]];
                    int p = atomicAdd(&cnt, 1);
                    if (p < HCAP) { ls_s[p] = si; ls_c[p] = cc[i]; ls_v[p] = vv[i]; }
                    else {
                        int pp = atomicAdd(&count[si], 1);
                        if (pp < MAXE)
                            csr2[(size_t)si * MAXE + pp] = make_int2(cc[i], __float_as_int(vv[i]));
                    }
                }
            }
        }
    }
    __syncthreads();

    int n = cnt; n = (n < HCAP) ? n : HCAP;
    for (int t2 = tid; t2 < n; t2 += 256) {
        int si = ls_s[t2];
        int p = atomicAdd(&count[si], 1);
        if (p < MAXE)
            csr2[(size_t)si * MAXE + p] = make_int2(ls_c[t2], __float_as_int(ls_v[t2]));
    }
}

// fused gather + MLP: 512-thread blocks (8 waves, 16 slots, 2 slots/wave).
// Wave-cap occupancy: 4 blocks/CU x 8 waves = 32 waves/CU (vs 20 with 256-thr).
// Both slots' first gather rounds issue all loads before any FMA.
__global__ void __launch_bounds__(512) k_gmlp(
        const int* __restrict__ users,
        const int* __restrict__ pos,
        const int* __restrict__ neg,
        const float* __restrict__ user_emb,
        const float* __restrict__ item_emb,
        const float* __restrict__ W_gc,
        const float* __restrict__ b_gc,
        const float* __restrict__ W_bi,
        const float* __restrict__ b_bi,
        const unsigned short* __restrict__ table16,
        const int* __restrict__ count,
        const int2* __restrict__ csr2,
        float* __restrict__ out) {
    __shared__ float wg[EMB * EMB];
    __shared__ float wb[EMB * EMB];
    int tid = threadIdx.x;
    int w = tid >> 6;
    int j = tid & 63;
    int sbase = blockIdx.x * 16 + w * 2;

    // stage layer-0 weights early; sync comes after the gather
    {
        const float4* g4 = (const float4*)W_gc;
        const float4* b4 = (const float4*)W_bi;
        float4* lg = (float4*)wg;
        float4* lb = (float4*)wb;
        #pragma unroll
        for (int i2 = tid; i2 < EMB * EMB / 4; i2 += 512) { lg[i2] = g4[i2]; lb[i2] = b4[i2]; }
    }

    // ---- phase 1: issue both slots' metadata chains ----
    float e[2];
    int   n[2];
    const int2* base[2];
    int2  ev[2];
    #pragma unroll
    for (int s = 0; s < 2; ++s) {
        int slot = sbase + s;
        int node;
        if (slot < BATCH)          node = users[slot];
        else if (slot < 2 * BATCH) node = N_USER + pos[slot - BATCH];
        else                       node = N_USER + neg[slot - 2 * BATCH];
        const float* erow = (node < N_USER) ? (user_emb + (size_t)node * EMB)
                                            : (item_emb + (size_t)(node - N_USER) * EMB);
        e[s] = erow[j];
        out[(size_t)slot * 256 + j] = e[s];       // layer-0 columns: raw ego

        int wslot = (int)table16[node];
        wslot = __builtin_amdgcn_readfirstlane(wslot);
        int nn = count[wslot];
        nn = (nn < MAXE) ? nn : MAXE;
        n[s] = __builtin_amdgcn_readfirstlane(nn);
        base[s] = csr2 + (size_t)wslot * MAXE;
        ev[s] = make_int2(0, 0);
        if (j < n[s]) ev[s] = base[s][j];         // lane j holds edge j
    }

    // ---- phase 2: first gather round for BOTH slots issued before any FMA ----
    float sval[2];
    {
        float vv[2][16], gg[2][16];
        #pragma unroll
        for (int s = 0; s < 2; ++s) {
            int m = (n[s] < 16) ? n[s] : 16;
            #pragma unroll
            for (int k = 0; k < 16; ++k) {
                bool okk = k < m;
                int   cc = __shfl(ev[s].x, k, 64);
                float vb = __uint_as_float((unsigned)__shfl(ev[s].y, k, 64));
                vv[s][k] = okk ? vb : 0.f;
                int ci = okk ? cc : 0;
                const float* sp = (ci < N_USER) ? (user_emb + (size_t)ci * EMB)
                                                : (item_emb + (size_t)(ci - N_USER) * EMB);
                gg[s][k] = sp[j];                 // 32 loads in flight
            }
        }
        #pragma unroll
        for (int s = 0; s < 2; ++s) {
            float acc = 0.f;
            #pragma unroll
            for (int k = 0; k < 16; ++k) acc = fmaf(vv[s][k], gg[s][k], acc);
            sval[s] = acc;
        }
    }
    // remaining rounds (n>16, uncommon; Poisson(13.3))
    #pragma unroll
    for (int s = 0; s < 2; ++s) {
        int m = (n[s] < 64) ? n[s] : 64;
        for (int tt = 16; tt < m; tt += 16) {
            float vv[16], gg[16];
            #pragma unroll
            for (int k = 0; k < 16; ++k) {
                int  t  = tt + k;
                bool okk = t < m;
                int   cc = __shfl(ev[s].x, t, 64);
                float vb = __uint_as_float((unsigned)__shfl(ev[s].y, t, 64));
                vv[k] = okk ? vb : 0.f;
                int ci = okk ? cc : 0;
                const float* sp = (ci < N_USER) ? (user_emb + (size_t)ci * EMB)
                                                : (item_emb + (size_t)(ci - N_USER) * EMB);
                gg[k] = sp[j];
            }
            #pragma unroll
            for (int k = 0; k < 16; ++k) sval[s] = fmaf(vv[k], gg[k], sval[s]);
        }
        for (int t = 64; t < n[s]; ++t) {         // essentially never
            int2 ee = base[s][t];
            const float* sp = (ee.x < N_USER) ? (user_emb + (size_t)ee.x * EMB)
                                              : (item_emb + (size_t)(ee.x - N_USER) * EMB);
            sval[s] = fmaf(__uint_as_float((unsigned)ee.y), sp[j], sval[s]);
        }
    }

    // ---- phase 3: 3-layer MLP ----
    for (int k = 0; k < N_LAYERS; ++k) {
        if (k == 0) {
            __syncthreads();                      // layer-0 weights staged
        } else {
            __syncthreads();                      // prev-layer LDS reads done
            const float4* g4 = (const float4*)(W_gc + (size_t)k * EMB * EMB);
            const float4* b4 = (const float4*)(W_bi + (size_t)k * EMB * EMB);
            float4* lg = (float4*)wg;
            float4* lb = (float4*)wb;
            #pragma unroll
            for (int i2 = tid; i2 < EMB * EMB / 4; i2 += 512) { lg[i2] = g4[i2]; lb[i2] = b4[i2]; }
            __syncthreads();                      // weights ready
        }

        float b1 = b_gc[k * EMB + j];
        float b2 = b_bi[k * EMB + j];
        float sum1[2], sum2[2], pv[2];
        #pragma unroll
        for (int s = 0; s < 2; ++s) { sum1[s] = b1; sum2[s] = b2; pv[s] = sval[s] * e[s]; }

        #pragma unroll 8
        for (int i = 0; i < EMB; ++i) {
            float wgi = wg[i * EMB + j];
            float wbi = wb[i * EMB + j];
            #pragma unroll
            for (int s = 0; s < 2; ++s) {
                float si = __uint_as_float(__builtin_amdgcn_readlane(__float_as_uint(sval[s]), i));
                float pi = __uint_as_float(__builtin_amdgcn_readlane(__float_as_uint(pv[s]),   i));
                sum1[s] = fmaf(si, wgi, sum1[s]);
                sum2[s] = fmaf(pi, wbi, sum2[s]);
            }
        }

        #pragma unroll
        for (int s = 0; s < 2; ++s) {
            float x = sum1[s] + sum2[s];
            x = (x >= 0.f) ? x : 0.2f * x;        // leaky_relu 0.2
            float sq = x * x;                     // wave-wide L2 norm
            #pragma unroll
            for (int o = 32; o; o >>= 1) sq += __shfl_xor(sq, o, 64);
            float nn2 = fmaxf(sqrtf(sq), 1e-12f);
            out[(size_t)(sbase + s) * 256 + (k + 1) * 64 + j] = x / nn2;
            e[s] = x;                             // next-layer ego = unnormalized output
        }
    }
}

extern "C" void kernel_launch(void* const* d_in, const int* in_sizes, int n_in,
                              void* d_out, int out_size, void* d_ws, size_t ws_size,
                              hipStream_t stream) {
    const int*   users    = (const int*)  d_in[0];
    const int*   pos      = (const int*)  d_in[1];
    const int*   neg      = (const int*)  d_in[2];
    const int*   row      = (const int*)  d_in[3];
    const int*   col      = (const int*)  d_in[4];
    const float* vals     = (const float*)d_in[5];
    const float* user_emb = (const float*)d_in[6];
    const float* item_emb = (const float*)d_in[7];
    const float* W_gc     = (const float*)d_in[8];
    const float* b_gc     = (const float*)d_in[9];
    const float* W_bi     = (const float*)d_in[10];
    const float* b_bi     = (const float*)d_in[11];
    float* out = (float*)d_out;

    char* ws = (char*)d_ws;
    unsigned short* table16 = (unsigned short*)ws;
    int*            count   = (int*)(ws + 600064);
    int2*           csr2    = (int2*)(ws + 649216);
    unsigned int*   bitmap  = (unsigned int*)(ws + 10086400);

    k_clear<<<(BM4 + 255) / 256, 256, 0, stream>>>((int4*)bitmap);
    k_setup<<<(NSLOT + 255) / 256, 256, 0, stream>>>(users, pos, neg, table16,
                                                     bitmap, count);
    k_build<<<(NNZ / 4 + 511) / 512, 256, 0, stream>>>(row, col, vals, bitmap,
                                                       table16, count, csr2);
    k_gmlp<<<NSLOT / 16, 512, 0, stream>>>(users, pos, neg, user_emb, item_emb,
                                           W_gc, b_gc, W_bi, b_bi,
                                           table16, count, csr2, out);
}